// Round 11
// baseline (368.887 us; speedup 1.0000x reference)
//
#include <hip/hip_runtime.h>
#include <hip/hip_bf16.h>
#include <stdint.h>

#define D_MODEL 1024
#define S_LEN   4096
#define BATCH   4
#define HEADS   16
#define DEPTH   64
#define ROWS    (BATCH*S_LEN)   // 16384
#define EPS_K_F 1e-6f
#define EPS_LN_F 1e-6f

typedef __attribute__((ext_vector_type(8))) short short8;
typedef __attribute__((ext_vector_type(4))) float f32x4;

__device__ __forceinline__ unsigned short f2bf(float f) {
  union { float f; unsigned u; } x; x.f = f;
  unsigned r = x.u + 0x7FFF + ((x.u >> 16) & 1);
  return (unsigned short)(r >> 16);
}
__device__ __forceinline__ float bf2f(unsigned short b) {
  union { unsigned u; float f; } x; x.u = ((unsigned)b) << 16;
  return x.f;
}
__device__ __forceinline__ void gload16(const void* g, void* l) {
  __builtin_amdgcn_global_load_lds(
      (const __attribute__((address_space(1))) void*)g,
      (__attribute__((address_space(3))) void*)l, 16, 0, 0);
}

// ---------------- fused f32 -> bf16 convert for q,k,v (streaming) -----------
// grid-stride, 8 floats/thread/iter: 2x float4 load -> 1x uint4 (16B) store.
// group index g in [0, 3*2^21); tb = g>>21 selects tensor (each 16.78M elems).
__global__ __launch_bounds__(256) void cvt3_k(
    const float* __restrict__ q, const float* __restrict__ k,
    const float* __restrict__ v,
    unsigned short* __restrict__ xq, unsigned short* __restrict__ xk,
    unsigned short* __restrict__ xv) {
  const int total = 3 << 21;               // 6291456 groups of 8 elems
  for (int g = blockIdx.x * 256 + threadIdx.x; g < total;
       g += gridDim.x * 256) {
    int tb = g >> 21;
    int i = g & ((1 << 21) - 1);
    const float* src = (tb == 0) ? q : (tb == 1) ? k : v;
    unsigned short* dst = (tb == 0) ? xq : (tb == 1) ? xk : xv;
    float4 a = ((const float4*)src)[i * 2];
    float4 b = ((const float4*)src)[i * 2 + 1];
    uint4 pk;
    pk.x = (unsigned)f2bf(a.x) | ((unsigned)f2bf(a.y) << 16);
    pk.y = (unsigned)f2bf(a.z) | ((unsigned)f2bf(a.w) << 16);
    pk.z = (unsigned)f2bf(b.x) | ((unsigned)f2bf(b.y) << 16);
    pk.w = (unsigned)f2bf(b.z) | ((unsigned)f2bf(b.w) << 16);
    ((uint4*)dst)[i] = pk;
  }
}

// ---------------- weight transpose + convert: W[K,N] f32 -> Wt[N,K] bf16 ----
__global__ __launch_bounds__(256) void wtrans_k(
    const float* __restrict__ W, unsigned short* __restrict__ Wt) {
  __shared__ float tile[32][33];
  int n0 = blockIdx.x * 32, k0 = blockIdx.y * 32;
  int tx = threadIdx.x & 31, ty = threadIdx.x >> 5;
  #pragma unroll
  for (int i = 0; i < 32; i += 8)
    tile[ty + i][tx] = W[(size_t)(k0 + ty + i) * D_MODEL + n0 + tx];
  __syncthreads();
  #pragma unroll
  for (int i = 0; i < 32; i += 8)
    Wt[(size_t)(n0 + ty + i) * D_MODEL + k0 + tx] = f2bf(tile[tx][ty + i]);
}

// ===== GEMM: 256x256 tile, 8 waves, BK=64, counted-vmcnt 4-phase pipeline ===
// (unchanged from R10 -- measured ~52 us/GEMM, ~20% above the 43 us
// staging-ingest floor of 262 MB at ~10 B/cyc/CU)

#define GEMM_EPILOGUE(HASBIAS)                                               \
  if (HASBIAS) {                                                             \
    float bv[4];                                                             \
    _Pragma("unroll")                                                        \
    for (int n = 0; n < 4; ++n)                                              \
      bv[n] = bias[(int)n0 + wcn * 64 + n * 16 + l15];                       \
    _Pragma("unroll")                                                        \
    for (int m = 0; m < 8; ++m)                                              \
      _Pragma("unroll")                                                      \
      for (int n = 0; n < 4; ++n)                                            \
        _Pragma("unroll")                                                    \
        for (int j = 0; j < 4; ++j)                                          \
          acc[m][n][j] += bv[n];                                             \
  }                                                                          \
  int seg = (int)(n0 >> 6) + wcn;                                            \
  _Pragma("unroll")                                                          \
  for (int m = 0; m < 8; ++m) {                                              \
    float s[4], s2[4];                                                       \
    _Pragma("unroll")                                                        \
    for (int j = 0; j < 4; ++j) {                                            \
      float a = 0.f, b = 0.f;                                                \
      _Pragma("unroll")                                                      \
      for (int n = 0; n < 4; ++n) { float x = acc[m][n][j]; a += x; b += x*x; } \
      s[j] = a; s2[j] = b;                                                   \
    }                                                                        \
    _Pragma("unroll")                                                        \
    for (int off = 1; off < 16; off <<= 1) {                                 \
      _Pragma("unroll")                                                      \
      for (int j = 0; j < 4; ++j) {                                          \
        s[j]  += __shfl_xor(s[j],  off);                                     \
        s2[j] += __shfl_xor(s2[j], off);                                     \
      }                                                                      \
    }                                                                        \
    if (l15 == 0) {                                                          \
      _Pragma("unroll")                                                      \
      for (int j = 0; j < 4; ++j) {                                          \
        int rg = (int)m0 + wr * 128 + m * 16 + lhi * 4 + j;                  \
        psum[rg * 16 + seg] = s[j];                                          \
        psq [rg * 16 + seg] = s2[j];                                         \
      }                                                                      \
    }                                                                        \
  }                                                                          \
  _Pragma("unroll")                                                          \
  for (int m = 0; m < 8; ++m)                                                \
    _Pragma("unroll")                                                        \
    for (int j = 0; j < 4; ++j) {                                            \
      size_t row = m0 + wr * 128 + m * 16 + lhi * 4 + j;                     \
      _Pragma("unroll")                                                      \
      for (int n = 0; n < 4; ++n) {                                          \
        int col = (int)n0 + wcn * 64 + n * 16 + l15;                         \
        Cb[row * N + col] = f2bf(acc[m][n][j]);                              \
      }                                                                      \
    }

#define STAGE_HALF(kof_, slot_, h_) do {                                     \
    _Pragma("unroll")                                                        \
    for (int j = 0; j < 2; ++j) {                                            \
      int idx = j * 512 + t; int r_ = idx >> 2; int cs_ = idx & 3;           \
      int c_ = cs_ ^ (r_ & 3);                                               \
      gload16(A + (m0 + r_) * (size_t)K + (kof_) + (h_) * 32 + c_ * 8,       \
              &Al[slot_][(h_) * 8192 + idx * 8]);                            \
    }                                                                        \
    _Pragma("unroll")                                                        \
    for (int j = 0; j < 2; ++j) {                                            \
      int idx = j * 512 + t; int r_ = idx >> 2; int cs_ = idx & 3;           \
      int c_ = cs_ ^ (r_ & 3);                                               \
      gload16(Bt + (n0 + r_) * (size_t)K + (kof_) + (h_) * 32 + c_ * 8,      \
              &Bl[slot_][(h_) * 8192 + idx * 8]);                            \
    }                                                                        \
  } while (0)

#define PH_READ_B(kk_)                                                       \
    _Pragma("unroll")                                                        \
    for (int n = 0; n < 4; ++n) {                                            \
      int rb_ = wcn * 64 + n * 16 + l15;                                     \
      bfr[n] = *(const short8*)&Bl[slot][(kk_) * 8192 + rb_ * 32 + cswz];    \
    }
#define PH_READ_A(kk_, mh_)                                                  \
    _Pragma("unroll")                                                        \
    for (int m = 0; m < 4; ++m) {                                            \
      int ra_ = wr * 128 + ((mh_) * 4 + m) * 16 + l15;                       \
      af[m] = *(const short8*)&Al[slot][(kk_) * 8192 + ra_ * 32 + cswz];     \
    }
#define PH_MFMA(mh_)                                                         \
    __builtin_amdgcn_s_setprio(1);                                           \
    _Pragma("unroll")                                                        \
    for (int m = 0; m < 4; ++m)                                              \
      _Pragma("unroll")                                                      \
      for (int n = 0; n < 4; ++n)                                            \
        acc[(mh_) * 4 + m][n] = __builtin_amdgcn_mfma_f32_16x16x32_bf16(     \
            af[m], bfr[n], acc[(mh_) * 4 + m][n], 0, 0, 0);                  \
    __builtin_amdgcn_s_setprio(0);
#define LGKM0                                                                \
    asm volatile("s_waitcnt lgkmcnt(0)" ::: "memory");                       \
    __builtin_amdgcn_sched_barrier(0);

__global__ __launch_bounds__(512, 2) void gemm_bt_k(
    const unsigned short* __restrict__ A,
    const unsigned short* __restrict__ Bt,
    unsigned short* __restrict__ Cb,
    float* __restrict__ psum, float* __restrict__ psq,
    const float* __restrict__ bias,
    int M, int N, int K) {
  __shared__ unsigned short Al[2][16384];
  __shared__ unsigned short Bl[2][16384];
  int t = threadIdx.x;
  int lane = t & 63, wid = t >> 6;
  int wr = wid >> 2, wcn = wid & 3;
  int l15 = lane & 15, lhi = lane >> 4;
  const int cswz = (lhi ^ (l15 & 3)) << 3;   // swizzled chunk byte-offset/2
  int p = blockIdx.x;
  int cb = (p >> 3) & 3;
  int rb = (p & 7) | ((p >> 5) << 3);
  size_t m0 = (size_t)rb * 256, n0 = (size_t)cb * 256;
  f32x4 acc[8][4] = {};

  const int KT = K >> 6;                  // 16 K-tiles of 64

  // prologue: tiles 0 and 1 (16 loads); wait tile 0 (keep tile 1 in flight)
  STAGE_HALF(0, 0, 0);  STAGE_HALF(0, 0, 1);
  STAGE_HALF(64, 1, 0); STAGE_HALF(64, 1, 1);
  asm volatile("s_waitcnt vmcnt(8)" ::: "memory");
  __builtin_amdgcn_s_barrier();
  __builtin_amdgcn_sched_barrier(0);

  for (int kt = 0; kt < KT; ++kt) {
    const int slot = kt & 1;
    short8 af[4], bfr[4];
    // phase 1: kk0, mh0
    PH_READ_B(0)
    PH_READ_A(0, 0)
    LGKM0
    PH_MFMA(0)
    // phase 2: kk0, mh1 (+ stage half0 of tile kt+2 into this slot)
    PH_READ_A(0, 1)
    LGKM0
    __builtin_amdgcn_s_barrier();          // all waves done with kk0 reads
    __builtin_amdgcn_sched_barrier(0);
    if (kt + 2 < KT) STAGE_HALF((kt + 2) << 6, slot, 0);
    __builtin_amdgcn_sched_barrier(0);
    PH_MFMA(1)
    // phase 3: kk1, mh0
    PH_READ_B(1)
    PH_READ_A(1, 0)
    LGKM0
    PH_MFMA(0)
    // phase 4: kk1, mh1 (+ stage half1 of tile kt+2)
    PH_READ_A(1, 1)
    LGKM0
    __builtin_amdgcn_s_barrier();          // all waves done with kk1 reads
    __builtin_amdgcn_sched_barrier(0);
    if (kt + 2 < KT) STAGE_HALF((kt + 2) << 6, slot, 1);
    __builtin_amdgcn_sched_barrier(0);
    PH_MFMA(1)
    // boundary: tile kt+1's loads (issued during kt-1) must have landed;
    // tile kt+2's 8 loads (issued just now) stay in flight.
    if (kt + 1 < KT) {
      if (kt + 2 < KT)
        asm volatile("s_waitcnt vmcnt(8)" ::: "memory");
      else
        asm volatile("s_waitcnt vmcnt(0)" ::: "memory");
      __builtin_amdgcn_s_barrier();
      __builtin_amdgcn_sched_barrier(0);
    }
  }

  GEMM_EPILOGUE(bias != nullptr)
}

// ---------------- LN + activation from bf16 C + partials -> bf16 ------------
// mode 0: relu(ln)+eps ; mode 1: (relu(ln)+eps)*mask ; mode 2: ln*mask
__global__ __launch_bounds__(256) void ln_act_k(
    const unsigned short* __restrict__ Cb,
    const float* __restrict__ psum, const float* __restrict__ psq,
    const float* __restrict__ gamma, const float* __restrict__ beta,
    const float* __restrict__ mask,
    unsigned short* __restrict__ out, int mode) {
  int row = blockIdx.x;
  int t = threadIdx.x;
  float s = 0.f, s2 = 0.f;
  #pragma unroll
  for (int i = 0; i < 16; ++i) { s += psum[row * 16 + i]; s2 += psq[row * 16 + i]; }
  float mean = s * (1.f / D_MODEL);
  float var = s2 * (1.f / D_MODEL) - mean * mean;
  float rstd = rsqrtf(var + EPS_LN_F);
  float mk = (mode > 0) ? mask[row] : 1.f;
  ushort4 cv = ((const ushort4*)(Cb + (size_t)row * D_MODEL))[t];
  float4 gv = ((const float4*)gamma)[t];
  float4 bv = ((const float4*)beta)[t];
  float av[4] = {bf2f(cv.x), bf2f(cv.y), bf2f(cv.z), bf2f(cv.w)};
  float g4[4] = {gv.x, gv.y, gv.z, gv.w};
  float b4[4] = {bv.x, bv.y, bv.z, bv.w};
  unsigned short ov[4];
  #pragma unroll
  for (int j = 0; j < 4; ++j) {
    float ln = (av[j] - mean) * rstd * g4[j] + b4[j];
    if (mode == 0)      ln = fmaxf(ln, 0.f) + EPS_K_F;
    else if (mode == 1) ln = (fmaxf(ln, 0.f) + EPS_K_F) * mk;
    else                ln = ln * mk;
    ov[j] = f2bf(ln);
  }
  ushort4 o; o.x = ov[0]; o.y = ov[1]; o.z = ov[2]; o.w = ov[3];
  ((ushort4*)(out + (size_t)row * D_MODEL))[t] = o;
}

// ---------------- final LayerNorm from bf16 C + partials -> f32 out ---------
__global__ __launch_bounds__(256) void ln_final_k(
    const unsigned short* __restrict__ Cb,
    const float* __restrict__ psum, const float* __restrict__ psq,
    const float* __restrict__ gamma, const float* __restrict__ beta,
    float* __restrict__ out) {
  int row = blockIdx.x;
  int t = threadIdx.x;
  float s = 0.f, s2 = 0.f;
  #pragma unroll
  for (int i = 0; i < 16; ++i) { s += psum[row * 16 + i]; s2 += psq[row * 16 + i]; }
  float mean = s * (1.f / D_MODEL);
  float var = s2 * (1.f / D_MODEL) - mean * mean;
  float rstd = rsqrtf(var + EPS_LN_F);
  ushort4 cv = ((const ushort4*)(Cb + (size_t)row * D_MODEL))[t];
  float4 gv = ((const float4*)gamma)[t];
  float4 bv = ((const float4*)beta)[t];
  float4 w;
  w.x = (bf2f(cv.x) - mean) * rstd * gv.x + bv.x;
  w.y = (bf2f(cv.y) - mean) * rstd * gv.y + bv.y;
  w.z = (bf2f(cv.z) - mean) * rstd * gv.z + bv.z;
  w.w = (bf2f(cv.w) - mean) * rstd * gv.w + bv.w;
  ((float4*)(out + (size_t)row * D_MODEL))[t] = w;
}

// ---------------- KV via MFMA with swizzled-LDS transpose -------------------
__global__ __launch_bounds__(256) void kv_mfma_k(
    const unsigned short* __restrict__ Kp, const unsigned short* __restrict__ Vp,
    float* __restrict__ part, float* __restrict__ kspart) {
  __shared__ unsigned short Kl[4096];
  __shared__ unsigned short Vl[4096];
  int bh = blockIdx.y, chunk = blockIdx.x;   // chunk 0..7, 512 n each
  int b_ = bh >> 4, h = bh & 15;
  int t = threadIdx.x, lane = t & 63, w = t >> 6;
  int l15 = lane & 15, g = lane >> 4;        // g in 0..3

  int sn = t >> 2, sd16 = t & 3;
  int sc = sd16 ^ ((sn >> 3) & 3);
  size_t goff = (size_t)sn * D_MODEL + h * DEPTH + sd16 * 16;
  int ldst = sn * 64 + sc * 16;

  short8 ones;
  #pragma unroll
  for (int i = 0; i < 8; ++i) ones[i] = (short)0x3F80;

  f32x4 acc[4] = {};
  f32x4 ks = {};

  int baseA = ((w ^ g) << 4) + l15;
  int baseB0 = ((0 ^ g) << 4) + l15;
  int baseB1 = ((1 ^ g) << 4) + l15;
  int baseB2 = ((2 ^ g) << 4) + l15;
  int baseB3 = ((3 ^ g) << 4) + l15;

  size_t rowbase = ((size_t)b_ * S_LEN + (size_t)chunk * 512) * D_MODEL;
  for (int tile = 0; tile < 8; ++tile) {
    const unsigned short* kg = Kp + rowbase + (size_t)tile * 64 * D_MODEL + goff;
    const unsigned short* vg = Vp + rowbase + (size_t)tile * 64 * D_MODEL + goff;
    uint4 ra = *(const uint4*)kg;
    uint4 rb = *(const uint4*)(kg + 8);
    uint4 rc = *(const uint4*)vg;
    uint4 rd = *(const uint4*)(vg + 8);
    __syncthreads();
    *(uint4*)&Kl[ldst]     = ra;
    *(uint4*)&Kl[ldst + 8] = rb;
    *(uint4*)&Vl[ldst]     = rc;
    *(uint4*)&Vl[ldst + 8] = rd;
    __syncthreads();
    #pragma unroll
    for (int kk = 0; kk < 2; ++kk) {
      int nb = (kk * 32 + g * 8) * 64;
      short8 af, bf0, bf1, bf2, bf3;
      #pragma unroll
      for (int i = 0; i < 8; ++i) {
        int rowoff = nb + i * 64;
        af[i]  = (short)Kl[rowoff + baseA];
        bf0[i] = (short)Vl[rowoff + baseB0];
        bf1[i] = (short)Vl[rowoff + baseB1];
        bf2[i] = (short)Vl[rowoff + baseB2];
        bf3[i] = (short)Vl[rowoff + baseB3];
      }
      acc[0] = __builtin_amdgcn_mfma_f32_16x16x32_bf16(af, bf0, acc[0], 0, 0, 0);
      acc[1] = __builtin_amdgcn_mfma_f32_16x16x32_bf16(af, bf1, acc[1], 0, 0, 0);
      acc[2] = __builtin_amdgcn_mfma_f32_16x16x32_bf16(af, bf2, acc[2], 0, 0, 0);
      acc[3] = __builtin_amdgcn_mfma_f32_16x16x32_bf16(af, bf3, acc[3], 0, 0, 0);
      ks     = __builtin_amdgcn_mfma_f32_16x16x32_bf16(af, ones, ks, 0, 0, 0);
    }
  }
  float* pp = part + ((size_t)bh * 8 + chunk) * 4096;
  #pragma unroll
  for (int nf = 0; nf < 4; ++nf)
    #pragma unroll
    for (int r = 0; r < 4; ++r)
      pp[(16 * w + 4 * g + r) * 64 + 16 * nf + l15] = acc[nf][r];
  if (l15 == 0) {
    #pragma unroll
    for (int r = 0; r < 4; ++r)
      kspart[((size_t)bh * 8 + chunk) * 64 + 16 * w + 4 * g + r] = ks[r];
  }
}

// ---------------- KV reduce -> KV^T bf16 ([e][d]) + ksum f32 ----------------
__global__ __launch_bounds__(256) void kv_reduce_k(
    const float* __restrict__ part, const float* __restrict__ kspart,
    unsigned short* __restrict__ KVT, float* __restrict__ ksum) {
  int bh = blockIdx.x, t = threadIdx.x;
  for (int idx = t; idx < 4096; idx += 256) {
    int d = idx >> 6, e = idx & 63;
    float s = 0.f;
    #pragma unroll
    for (int c = 0; c < 8; ++c)
      s += part[((size_t)bh * 8 + c) * 4096 + d * 64 + e];
    KVT[(size_t)bh * 4096 + e * 64 + d] = f2bf(s);
  }
  if (t < 64) {
    float s = 0.f;
    #pragma unroll
    for (int c = 0; c < 8; ++c) s += kspart[((size_t)bh * 8 + c) * 64 + t];
    ksum[bh * 64 + t] = s;
  }
}

// ---------------- att = (q' @ KV) * z, written in the reference's reshape ---
__global__ __launch_bounds__(256) void att_k(
    const unsigned short* __restrict__ Qp, const unsigned short* __restrict__ KVT,
    const float* __restrict__ ksum, unsigned short* __restrict__ att) {
  __shared__ unsigned short Ql[128 * 64];
  __shared__ unsigned short Kl[64 * 64];
  __shared__ float ksl[64];
  __shared__ float zl[128];
  int bh = blockIdx.y;
  int b = bh >> 4, h = bh & 15;
  int r0 = blockIdx.x * 128;
  int t = threadIdx.x, lane = t & 63, wid = t >> 6;
  int l15 = lane & 15, lhi = lane >> 4;
  #pragma unroll
  for (int i = 0; i < 4; ++i) {
    int cid = i * 256 + t;
    int r = cid >> 3, c8 = cid & 7;
    gload16(Qp + ((size_t)(b * S_LEN + r0 + r)) * D_MODEL + h * DEPTH + c8 * 8,
            &Ql[cid * 8]);
  }
  #pragma unroll
  for (int i = 0; i < 2; ++i) {
    int cid = i * 256 + t;
    gload16(KVT + (size_t)bh * 4096 + cid * 8, &Kl[cid * 8]);
  }
  if (t < 64) ksl[t] = ksum[bh * 64 + t];
  asm volatile("s_waitcnt vmcnt(0)" ::: "memory");
  __syncthreads();
  {
    int r = t >> 1, half = t & 1;
    float s = 0.f;
    #pragma unroll
    for (int j = 0; j < 32; ++j)
      s += bf2f(Ql[r * 64 + half * 32 + j]) * ksl[half * 32 + j];
    s += __shfl_xor(s, 1);
    if (half == 0) zl[r] = 1.f / (s + EPS_K_F);
  }
  __syncthreads();
  f32x4 acc[2][4] = {};
  #pragma unroll
  for (int kk = 0; kk < 2; ++kk) {
    short8 af[2], bfr[4];
    #pragma unroll
    for (int m = 0; m < 2; ++m)
      af[m] = *(const short8*)&Ql[(wid * 32 + m * 16 + l15) * 64 + kk * 32 + lhi * 8];
    #pragma unroll
    for (int n = 0; n < 4; ++n)
      bfr[n] = *(const short8*)&Kl[(n * 16 + l15) * 64 + kk * 32 + lhi * 8];
    #pragma unroll
    for (int m = 0; m < 2; ++m)
      #pragma unroll
      for (int n = 0; n < 4; ++n)
        acc[m][n] = __builtin_amdgcn_mfma_f32_16x16x32_bf16(af[m], bfr[n], acc[m][n], 0, 0, 0);
  }
  #pragma unroll
  for (int m = 0; m < 2; ++m)
    #pragma unroll
    for (int j = 0; j < 4; ++j) {
      int rl = wid * 32 + m * 16 + lhi * 4 + j;
      int n = r0 + rl;
      float z = zl[rl];
      #pragma unroll
      for (int nf = 0; nf < 4; ++nf) {
        int ee = nf * 16 + l15;
        size_t orow = (size_t)b * S_LEN + h * 256 + (n >> 4);
        int ocol = (n & 15) * 64 + ee;
        att[orow * D_MODEL + ocol] = f2bf(acc[m][nf][j] * z);
      }
    }
}

extern "C" void kernel_launch(void* const* d_in, const int* in_sizes, int n_in,
                              void* d_out, int out_size, void* d_ws, size_t ws_size,
                              hipStream_t stream) {
  (void)in_sizes; (void)n_in; (void)out_size; (void)ws_size;
  const float* q     = (const float*)d_in[0];
  const float* k     = (const float*)d_in[1];
  const float* v     = (const float*)d_in[2];
  const float* mask  = (const float*)d_in[3];
  const float* wq    = (const float*)d_in[4];
  const float* wk    = (const float*)d_in[5];
  const float* wv    = (const float*)d_in[6];
  const float* gamma = (const float*)d_in[7];
  const float* beta  = (const float*)d_in[8];
  const float* dw    = (const float*)d_in[9];
  const float* db    = (const float*)d_in[10];
  float* out = (float*)d_out;

  char* ws = (char*)d_ws;
  // buffer plan (lifetimes hand-verified):
  //   ws+0   : Xq (cvt3) -> dead after gemm_q -> Qp (ln_act) -> dead after
  //            att -> Cd (dense C).
  //   ws+32M : Xk -> dead after gemm_k -> Kp (ln_act) -> dead after kv_mfma.
  //   ws+64M : Xv -> dead after gemm_v -> Vp (ln_act) -> dead after kv_mfma.
  //   ws+96M : weights (8 MB); ws+104M: part (8 MB); ws+112M: kspart/KVT/
  //            ksum; ws+115M/116M: psum/psq.
  //   d_out  : bf16 C scratch for q/k/v GEMMs + att output (first 32 MB),
  //            fully overwritten by ln_final at the end.
  unsigned short* Xq  = (unsigned short*)(ws);
  unsigned short* Xk  = (unsigned short*)(ws + 33554432);
  unsigned short* Xv  = (unsigned short*)(ws + 67108864);
  unsigned short* Qp  = Xq;
  unsigned short* Kp  = Xk;
  unsigned short* Vp  = Xv;
  unsigned short* Cd  = Xq;                 // dense C after att consumed Qp
  unsigned short* WqT = (unsigned short*)(ws + 100663296);
  unsigned short* WkT = WqT + 1048576;
  unsigned short* WvT = WkT + 1048576;
  unsigned short* WdT = WvT + 1048576;
  float* part   = (float*)(ws + 109051904);
  float* kspart = (float*)(ws + 117440512);
  unsigned short* KVT = (unsigned short*)(ws + 117964800);
  float* ksum = (float*)(ws + 118489088);
  float* psum = (float*)(ws + 119537664);   // 1 MB
  float* psq  = (float*)(ws + 120586240);   // 1 MB
  unsigned short* Cqkv = (unsigned short*)d_out;   // bf16 C scratch / att out

  dim3 b256(256);
  dim3 b512(512);
  dim3 wtg(32, 32);
  dim3 gemmg(256);            // (M/256)*(N/256), XCD-swizzled in-kernel
  dim3 lng(ROWS);

  wtrans_k<<<wtg, b256, 0, stream>>>(wq, WqT);
  wtrans_k<<<wtg, b256, 0, stream>>>(wk, WkT);
  wtrans_k<<<wtg, b256, 0, stream>>>(wv, WvT);
  wtrans_k<<<wtg, b256, 0, stream>>>(dw, WdT);

  cvt3_k<<<dim3(2048), b256, 0, stream>>>(q, k, v, Xq, Xk, Xv);

  gemm_bt_k<<<gemmg, b512, 0, stream>>>(Xq, WqT, Cqkv, psum, psq, nullptr,
                                        ROWS, D_MODEL, D_MODEL);
  ln_act_k<<<lng, b256, 0, stream>>>(Cqkv, psum, psq, gamma, beta, nullptr, Qp, 0);

  gemm_bt_k<<<gemmg, b512, 0, stream>>>(Xk, WkT, Cqkv, psum, psq, nullptr,
                                        ROWS, D_MODEL, D_MODEL);
  ln_act_k<<<lng, b256, 0, stream>>>(Cqkv, psum, psq, gamma, beta, mask, Kp, 1);

  gemm_bt_k<<<gemmg, b512, 0, stream>>>(Xv, WvT, Cqkv, psum, psq, nullptr,
                                        ROWS, D_MODEL, D_MODEL);
  ln_act_k<<<lng, b256, 0, stream>>>(Cqkv, psum, psq, gamma, beta, mask, Vp, 2);

  kv_mfma_k<<<dim3(8, 64), b256, 0, stream>>>(Kp, Vp, part, kspart);
  kv_reduce_k<<<dim3(64), b256, 0, stream>>>(part, kspart, KVT, ksum);
  att_k<<<dim3(32, 64), b256, 0, stream>>>(Qp, KVT, ksum, Cqkv);

  gemm_bt_k<<<gemmg, b512, 0, stream>>>(Cqkv, WdT, Cd, psum, psq, db,
                                        ROWS, D_MODEL, D_MODEL);
  ln_final_k<<<lng, b256, 0, stream>>>(Cd, psum, psq, gamma, beta, out);
}

// Round 12
// 353.294 us; speedup vs baseline: 1.0441x; 1.0441x over previous
//
#include <hip/hip_runtime.h>
#include <hip/hip_bf16.h>
#include <stdint.h>

#define D_MODEL 1024
#define S_LEN   4096
#define BATCH   4
#define HEADS   16
#define DEPTH   64
#define ROWS    (BATCH*S_LEN)   // 16384
#define EPS_K_F 1e-6f
#define EPS_LN_F 1e-6f

typedef __attribute__((ext_vector_type(8))) short short8;
typedef __attribute__((ext_vector_type(4))) float f32x4;

__device__ __forceinline__ unsigned short f2bf(float f) {
  union { float f; unsigned u; } x; x.f = f;
  unsigned r = x.u + 0x7FFF + ((x.u >> 16) & 1);
  return (unsigned short)(r >> 16);
}
__device__ __forceinline__ float bf2f(unsigned short b) {
  union { unsigned u; float f; } x; x.u = ((unsigned)b) << 16;
  return x.f;
}
__device__ __forceinline__ void gload16(const void* g, void* l) {
  __builtin_amdgcn_global_load_lds(
      (const __attribute__((address_space(1))) void*)g,
      (__attribute__((address_space(3))) void*)l, 16, 0, 0);
}

// ---------------- f32 -> bf16 convert (q only; k,v ride GEMM sidecars) ------
__global__ __launch_bounds__(256) void cvt_f32_bf16_k(
    const float* __restrict__ in, unsigned short* __restrict__ out, int n4) {
  int i = blockIdx.x * 256 + threadIdx.x;
  if (i < n4) {
    float4 v = ((const float4*)in)[i];
    ushort4 o;
    o.x = f2bf(v.x); o.y = f2bf(v.y); o.z = f2bf(v.z); o.w = f2bf(v.w);
    ((ushort4*)out)[i] = o;
  }
}

// ---------------- weight transpose + convert: W[K,N] f32 -> Wt[N,K] bf16 ----
__global__ __launch_bounds__(256) void wtrans_k(
    const float* __restrict__ W, unsigned short* __restrict__ Wt) {
  __shared__ float tile[32][33];
  int n0 = blockIdx.x * 32, k0 = blockIdx.y * 32;
  int tx = threadIdx.x & 31, ty = threadIdx.x >> 5;
  #pragma unroll
  for (int i = 0; i < 32; i += 8)
    tile[ty + i][tx] = W[(size_t)(k0 + ty + i) * D_MODEL + n0 + tx];
  __syncthreads();
  #pragma unroll
  for (int i = 0; i < 32; i += 8)
    Wt[(size_t)(n0 + ty + i) * D_MODEL + k0 + tx] = f2bf(tile[tx][ty + i]);
}

// ===== GEMM: 256x256 tile, 8 waves, BK=64, counted-vmcnt 4-phase pipeline ===
// Main loop peeled to kt < KT-2 so staging is UNCONDITIONAL (compiler's
// static vmcnt tracking stays precise); last two K-tiles are tail blocks.
// Optional SIDECAR (template) converts an independent f32 tensor to bf16:
// chunk kt's loads issue at boundary kt-1 (chunk 0 before prologue staging),
// pack+store at boundary kt. Compiler's wait before the pack (L_kt is
// 8-staging-ops old) == vmcnt(8) == the boundary's stage-drain requirement;
// explicit boundary wait is vmcnt(11) (8 staging + S + 2 L in flight).
// In-order vmcnt retirement makes draining L_kt imply draining stage(kt+1).

#define GEMM_EPILOGUE(HASBIAS)                                               \
  if (HASBIAS) {                                                             \
    float bv[4];                                                             \
    _Pragma("unroll")                                                        \
    for (int n = 0; n < 4; ++n)                                              \
      bv[n] = bias[(int)n0 + wcn * 64 + n * 16 + l15];                       \
    _Pragma("unroll")                                                        \
    for (int m = 0; m < 8; ++m)                                              \
      _Pragma("unroll")                                                      \
      for (int n = 0; n < 4; ++n)                                            \
        _Pragma("unroll")                                                    \
        for (int j = 0; j < 4; ++j)                                          \
          acc[m][n][j] += bv[n];                                             \
  }                                                                          \
  int seg = (int)(n0 >> 6) + wcn;                                            \
  _Pragma("unroll")                                                          \
  for (int m = 0; m < 8; ++m) {                                              \
    float s[4], s2[4];                                                       \
    _Pragma("unroll")                                                        \
    for (int j = 0; j < 4; ++j) {                                            \
      float a = 0.f, b = 0.f;                                                \
      _Pragma("unroll")                                                      \
      for (int n = 0; n < 4; ++n) { float x = acc[m][n][j]; a += x; b += x*x; } \
      s[j] = a; s2[j] = b;                                                   \
    }                                                                        \
    _Pragma("unroll")                                                        \
    for (int off = 1; off < 16; off <<= 1) {                                 \
      _Pragma("unroll")                                                      \
      for (int j = 0; j < 4; ++j) {                                          \
        s[j]  += __shfl_xor(s[j],  off);                                     \
        s2[j] += __shfl_xor(s2[j], off);                                     \
      }                                                                      \
    }                                                                        \
    if (l15 == 0) {                                                          \
      _Pragma("unroll")                                                      \
      for (int j = 0; j < 4; ++j) {                                          \
        int rg = (int)m0 + wr * 128 + m * 16 + lhi * 4 + j;                  \
        psum[rg * 16 + seg] = s[j];                                          \
        psq [rg * 16 + seg] = s2[j];                                         \
      }                                                                      \
    }                                                                        \
  }                                                                          \
  _Pragma("unroll")                                                          \
  for (int m = 0; m < 8; ++m)                                                \
    _Pragma("unroll")                                                        \
    for (int j = 0; j < 4; ++j) {                                            \
      size_t row = m0 + wr * 128 + m * 16 + lhi * 4 + j;                     \
      _Pragma("unroll")                                                      \
      for (int n = 0; n < 4; ++n) {                                          \
        int col = (int)n0 + wcn * 64 + n * 16 + l15;                         \
        Cb[row * N + col] = f2bf(acc[m][n][j]);                              \
      }                                                                      \
    }

#define STAGE_HALF(kof_, slot_, h_) do {                                     \
    _Pragma("unroll")                                                        \
    for (int j = 0; j < 2; ++j) {                                            \
      int idx = j * 512 + t; int r_ = idx >> 2; int cs_ = idx & 3;           \
      int c_ = cs_ ^ (r_ & 3);                                               \
      gload16(A + (m0 + r_) * (size_t)K + (kof_) + (h_) * 32 + c_ * 8,       \
              &Al[slot_][(h_) * 8192 + idx * 8]);                            \
    }                                                                        \
    _Pragma("unroll")                                                        \
    for (int j = 0; j < 2; ++j) {                                            \
      int idx = j * 512 + t; int r_ = idx >> 2; int cs_ = idx & 3;           \
      int c_ = cs_ ^ (r_ & 3);                                               \
      gload16(Bt + (n0 + r_) * (size_t)K + (kof_) + (h_) * 32 + c_ * 8,      \
              &Bl[slot_][(h_) * 8192 + idx * 8]);                            \
    }                                                                        \
  } while (0)

#define PH_READ_B(kk_)                                                       \
    _Pragma("unroll")                                                        \
    for (int n = 0; n < 4; ++n) {                                            \
      int rb_ = wcn * 64 + n * 16 + l15;                                     \
      bfr[n] = *(const short8*)&Bl[slot][(kk_) * 8192 + rb_ * 32 + cswz];    \
    }
#define PH_READ_A(kk_, mh_)                                                  \
    _Pragma("unroll")                                                        \
    for (int m = 0; m < 4; ++m) {                                            \
      int ra_ = wr * 128 + ((mh_) * 4 + m) * 16 + l15;                       \
      af[m] = *(const short8*)&Al[slot][(kk_) * 8192 + ra_ * 32 + cswz];     \
    }
#define PH_MFMA(mh_)                                                         \
    __builtin_amdgcn_s_setprio(1);                                           \
    _Pragma("unroll")                                                        \
    for (int m = 0; m < 4; ++m)                                              \
      _Pragma("unroll")                                                      \
      for (int n = 0; n < 4; ++n)                                            \
        acc[(mh_) * 4 + m][n] = __builtin_amdgcn_mfma_f32_16x16x32_bf16(     \
            af[m], bfr[n], acc[(mh_) * 4 + m][n], 0, 0, 0);                  \
    __builtin_amdgcn_s_setprio(0);
#define LGKM0                                                                \
    asm volatile("s_waitcnt lgkmcnt(0)" ::: "memory");                       \
    __builtin_amdgcn_sched_barrier(0);

#define SIDE_PACK_STORE(chunk_) do {                                         \
    uint4 pk_;                                                               \
    pk_.x = (unsigned)f2bf(sreg0.x) | ((unsigned)f2bf(sreg0.y) << 16);       \
    pk_.y = (unsigned)f2bf(sreg0.z) | ((unsigned)f2bf(sreg0.w) << 16);       \
    pk_.z = (unsigned)f2bf(sreg1.x) | ((unsigned)f2bf(sreg1.y) << 16);       \
    pk_.w = (unsigned)f2bf(sreg1.z) | ((unsigned)f2bf(sreg1.w) << 16);       \
    *(uint4*)(side_dst + sbase + (size_t)(chunk_) * 4096) = pk_;             \
  } while (0)
#define SIDE_LOAD(chunk_) do {                                               \
    const float* sp_ = side_src + sbase + (size_t)(chunk_) * 4096;           \
    sreg0 = *(const float4*)sp_; sreg1 = *(const float4*)(sp_ + 4);          \
  } while (0)

#define TAIL_TILE(slot_) do {                                                \
    const int slot = (slot_);                                                \
    short8 af[4], bfr[4];                                                    \
    PH_READ_B(0) PH_READ_A(0, 0) LGKM0 PH_MFMA(0)                            \
    PH_READ_A(0, 1) LGKM0 PH_MFMA(1)                                         \
    PH_READ_B(1) PH_READ_A(1, 0) LGKM0 PH_MFMA(0)                            \
    PH_READ_A(1, 1) LGKM0 PH_MFMA(1)                                         \
  } while (0)

template <bool SIDECAR>
__global__ __launch_bounds__(512) void gemm_bt_k(
    const unsigned short* __restrict__ A,
    const unsigned short* __restrict__ Bt,
    unsigned short* __restrict__ Cb,
    float* __restrict__ psum, float* __restrict__ psq,
    const float* __restrict__ bias,
    const float* __restrict__ side_src,      // f32 tensor to convert
    unsigned short* __restrict__ side_dst,   // bf16 destination
    int M, int N, int K) {
  __shared__ unsigned short Al[2][16384];
  __shared__ unsigned short Bl[2][16384];
  int t = threadIdx.x;
  int lane = t & 63, wid = t >> 6;
  int wr = wid >> 2, wcn = wid & 3;
  int l15 = lane & 15, lhi = lane >> 4;
  const int cswz = (lhi ^ (l15 & 3)) << 3;   // swizzled chunk offset (bf16)
  int p = blockIdx.x;
  int cb = (p >> 3) & 3;
  int rb = (p & 7) | ((p >> 5) << 3);
  size_t m0 = (size_t)rb * 256, n0 = (size_t)cb * 256;
  f32x4 acc[8][4] = {};

  const int KT = K >> 6;                  // 16 K-tiles of 64 (K==1024)

  // sidecar: block p converts elems [p*65536,(p+1)*65536), 16 chunks of 4096
  float4 sreg0 = {}, sreg1 = {};
  size_t sbase = (size_t)p * 65536 + (size_t)t * 8;

  // prologue: chunk-0 load FIRST, then stage tiles 0,1; vmcnt(8) drains
  // chunk-0 loads + tile-0 staging, keeps tile-1 staging (8) in flight.
  if (SIDECAR) SIDE_LOAD(0);
  STAGE_HALF(0, 0, 0);  STAGE_HALF(0, 0, 1);
  STAGE_HALF(64, 1, 0); STAGE_HALF(64, 1, 1);
  asm volatile("s_waitcnt vmcnt(8)" ::: "memory");
  __builtin_amdgcn_s_barrier();
  __builtin_amdgcn_sched_barrier(0);

  for (int kt = 0; kt < KT - 2; ++kt) {
    const int slot = kt & 1;
    short8 af[4], bfr[4];
    // phase 1: kk0, mh0
    PH_READ_B(0)
    PH_READ_A(0, 0)
    LGKM0
    PH_MFMA(0)
    // phase 2: kk0, mh1 (+ stage half0 of tile kt+2 into this slot)
    PH_READ_A(0, 1)
    LGKM0
    __builtin_amdgcn_s_barrier();          // all waves done with kk0 reads
    __builtin_amdgcn_sched_barrier(0);
    STAGE_HALF((kt + 2) << 6, slot, 0);
    __builtin_amdgcn_sched_barrier(0);
    PH_MFMA(1)
    // phase 3: kk1, mh0
    PH_READ_B(1)
    PH_READ_A(1, 0)
    LGKM0
    PH_MFMA(0)
    // phase 4: kk1, mh1 (+ stage half1 of tile kt+2)
    PH_READ_A(1, 1)
    LGKM0
    __builtin_amdgcn_s_barrier();          // all waves done with kk1 reads
    __builtin_amdgcn_sched_barrier(0);
    STAGE_HALF((kt + 2) << 6, slot, 1);
    __builtin_amdgcn_sched_barrier(0);
    PH_MFMA(1)
    // boundary
    if (SIDECAR) {
      // pack chunk kt (compiler's wait for sreg == vmcnt(8): also drains
      // stage(kt+1) by in-order retirement), store it, load chunk kt+1.
      SIDE_PACK_STORE(kt);
      SIDE_LOAD(kt + 1);
      __builtin_amdgcn_sched_barrier(0);
      asm volatile("s_waitcnt vmcnt(11)" ::: "memory");
    } else {
      asm volatile("s_waitcnt vmcnt(8)" ::: "memory");
    }
    __builtin_amdgcn_s_barrier();
    __builtin_amdgcn_sched_barrier(0);
  }

  // tail tile KT-2 (slot 0): no staging
  TAIL_TILE((KT - 2) & 1);
  if (SIDECAR) {
    SIDE_PACK_STORE(KT - 2);
    SIDE_LOAD(KT - 1);
    __builtin_amdgcn_sched_barrier(0);
    asm volatile("s_waitcnt vmcnt(3)" ::: "memory");  // drain stage(KT-1)
  } else {
    asm volatile("s_waitcnt vmcnt(0)" ::: "memory");
  }
  __builtin_amdgcn_s_barrier();
  __builtin_amdgcn_sched_barrier(0);

  // tail tile KT-1 (slot 1): no staging, no boundary
  TAIL_TILE((KT - 1) & 1);
  if (SIDECAR) SIDE_PACK_STORE(KT - 1);

  GEMM_EPILOGUE(bias != nullptr)
}

// ---------------- LN + activation from bf16 C + partials -> bf16 ------------
// mode 0: relu(ln)+eps ; mode 1: (relu(ln)+eps)*mask ; mode 2: ln*mask
__global__ __launch_bounds__(256) void ln_act_k(
    const unsigned short* __restrict__ Cb,
    const float* __restrict__ psum, const float* __restrict__ psq,
    const float* __restrict__ gamma, const float* __restrict__ beta,
    const float* __restrict__ mask,
    unsigned short* __restrict__ out, int mode) {
  int row = blockIdx.x;
  int t = threadIdx.x;
  float s = 0.f, s2 = 0.f;
  #pragma unroll
  for (int i = 0; i < 16; ++i) { s += psum[row * 16 + i]; s2 += psq[row * 16 + i]; }
  float mean = s * (1.f / D_MODEL);
  float var = s2 * (1.f / D_MODEL) - mean * mean;
  float rstd = rsqrtf(var + EPS_LN_F);
  float mk = (mode > 0) ? mask[row] : 1.f;
  ushort4 cv = ((const ushort4*)(Cb + (size_t)row * D_MODEL))[t];
  float4 gv = ((const float4*)gamma)[t];
  float4 bv = ((const float4*)beta)[t];
  float av[4] = {bf2f(cv.x), bf2f(cv.y), bf2f(cv.z), bf2f(cv.w)};
  float g4[4] = {gv.x, gv.y, gv.z, gv.w};
  float b4[4] = {bv.x, bv.y, bv.z, bv.w};
  unsigned short ov[4];
  #pragma unroll
  for (int j = 0; j < 4; ++j) {
    float ln = (av[j] - mean) * rstd * g4[j] + b4[j];
    if (mode == 0)      ln = fmaxf(ln, 0.f) + EPS_K_F;
    else if (mode == 1) ln = (fmaxf(ln, 0.f) + EPS_K_F) * mk;
    else                ln = ln * mk;
    ov[j] = f2bf(ln);
  }
  ushort4 o; o.x = ov[0]; o.y = ov[1]; o.z = ov[2]; o.w = ov[3];
  ((ushort4*)(out + (size_t)row * D_MODEL))[t] = o;
}

// ---------------- final LayerNorm from bf16 C + partials -> f32 out ---------
__global__ __launch_bounds__(256) void ln_final_k(
    const unsigned short* __restrict__ Cb,
    const float* __restrict__ psum, const float* __restrict__ psq,
    const float* __restrict__ gamma, const float* __restrict__ beta,
    float* __restrict__ out) {
  int row = blockIdx.x;
  int t = threadIdx.x;
  float s = 0.f, s2 = 0.f;
  #pragma unroll
  for (int i = 0; i < 16; ++i) { s += psum[row * 16 + i]; s2 += psq[row * 16 + i]; }
  float mean = s * (1.f / D_MODEL);
  float var = s2 * (1.f / D_MODEL) - mean * mean;
  float rstd = rsqrtf(var + EPS_LN_F);
  ushort4 cv = ((const ushort4*)(Cb + (size_t)row * D_MODEL))[t];
  float4 gv = ((const float4*)gamma)[t];
  float4 bv = ((const float4*)beta)[t];
  float4 w;
  w.x = (bf2f(cv.x) - mean) * rstd * gv.x + bv.x;
  w.y = (bf2f(cv.y) - mean) * rstd * gv.y + bv.y;
  w.z = (bf2f(cv.z) - mean) * rstd * gv.z + bv.z;
  w.w = (bf2f(cv.w) - mean) * rstd * gv.w + bv.w;
  ((float4*)(out + (size_t)row * D_MODEL))[t] = w;
}

// ---------------- KV via MFMA with swizzled-LDS transpose -------------------
__global__ __launch_bounds__(256) void kv_mfma_k(
    const unsigned short* __restrict__ Kp, const unsigned short* __restrict__ Vp,
    float* __restrict__ part, float* __restrict__ kspart) {
  __shared__ unsigned short Kl[4096];
  __shared__ unsigned short Vl[4096];
  int bh = blockIdx.y, chunk = blockIdx.x;   // chunk 0..7, 512 n each
  int b_ = bh >> 4, h = bh & 15;
  int t = threadIdx.x, lane = t & 63, w = t >> 6;
  int l15 = lane & 15, g = lane >> 4;        // g in 0..3

  int sn = t >> 2, sd16 = t & 3;
  int sc = sd16 ^ ((sn >> 3) & 3);
  size_t goff = (size_t)sn * D_MODEL + h * DEPTH + sd16 * 16;
  int ldst = sn * 64 + sc * 16;

  short8 ones;
  #pragma unroll
  for (int i = 0; i < 8; ++i) ones[i] = (short)0x3F80;

  f32x4 acc[4] = {};
  f32x4 ks = {};

  int baseA = ((w ^ g) << 4) + l15;
  int baseB0 = ((0 ^ g) << 4) + l15;
  int baseB1 = ((1 ^ g) << 4) + l15;
  int baseB2 = ((2 ^ g) << 4) + l15;
  int baseB3 = ((3 ^ g) << 4) + l15;

  size_t rowbase = ((size_t)b_ * S_LEN + (size_t)chunk * 512) * D_MODEL;
  for (int tile = 0; tile < 8; ++tile) {
    const unsigned short* kg = Kp + rowbase + (size_t)tile * 64 * D_MODEL + goff;
    const unsigned short* vg = Vp + rowbase + (size_t)tile * 64 * D_MODEL + goff;
    uint4 ra = *(const uint4*)kg;
    uint4 rb = *(const uint4*)(kg + 8);
    uint4 rc = *(const uint4*)vg;
    uint4 rd = *(const uint4*)(vg + 8);
    __syncthreads();
    *(uint4*)&Kl[ldst]     = ra;
    *(uint4*)&Kl[ldst + 8] = rb;
    *(uint4*)&Vl[ldst]     = rc;
    *(uint4*)&Vl[ldst + 8] = rd;
    __syncthreads();
    #pragma unroll
    for (int kk = 0; kk < 2; ++kk) {
      int nb = (kk * 32 + g * 8) * 64;
      short8 af, bf0, bf1, bf2, bf3;
      #pragma unroll
      for (int i = 0; i < 8; ++i) {
        int rowoff = nb + i * 64;
        af[i]  = (short)Kl[rowoff + baseA];
        bf0[i] = (short)Vl[rowoff + baseB0];
        bf1[i] = (short)Vl[rowoff + baseB1];
        bf2[i] = (short)Vl[rowoff + baseB2];
        bf3[i] = (short)Vl[rowoff + baseB3];
      }
      acc[0] = __builtin_amdgcn_mfma_f32_16x16x32_bf16(af, bf0, acc[0], 0, 0, 0);
      acc[1] = __builtin_amdgcn_mfma_f32_16x16x32_bf16(af, bf1, acc[1], 0, 0, 0);
      acc[2] = __builtin_amdgcn_mfma_f32_16x16x32_bf16(af, bf2, acc[2], 0, 0, 0);
      acc[3] = __builtin_amdgcn_mfma_f32_16x16x32_bf16(af, bf3, acc[3], 0, 0, 0);
      ks     = __builtin_amdgcn_mfma_f32_16x16x32_bf16(af, ones, ks, 0, 0, 0);
    }
  }
  float* pp = part + ((size_t)bh * 8 + chunk) * 4096;
  #pragma unroll
  for (int nf = 0; nf < 4; ++nf)
    #pragma unroll
    for (int r = 0; r < 4; ++r)
      pp[(16 * w + 4 * g + r) * 64 + 16 * nf + l15] = acc[nf][r];
  if (l15 == 0) {
    #pragma unroll
    for (int r = 0; r < 4; ++r)
      kspart[((size_t)bh * 8 + chunk) * 64 + 16 * w + 4 * g + r] = ks[r];
  }
}

// ---------------- KV reduce -> KV^T bf16 ([e][d]) + ksum f32 ----------------
__global__ __launch_bounds__(256) void kv_reduce_k(
    const float* __restrict__ part, const float* __restrict__ kspart,
    unsigned short* __restrict__ KVT, float* __restrict__ ksum) {
  int bh = blockIdx.x, t = threadIdx.x;
  for (int idx = t; idx < 4096; idx += 256) {
    int d = idx >> 6, e = idx & 63;
    float s = 0.f;
    #pragma unroll
    for (int c = 0; c < 8; ++c)
      s += part[((size_t)bh * 8 + c) * 4096 + d * 64 + e];
    KVT[(size_t)bh * 4096 + e * 64 + d] = f2bf(s);
  }
  if (t < 64) {
    float s = 0.f;
    #pragma unroll
    for (int c = 0; c < 8; ++c) s += kspart[((size_t)bh * 8 + c) * 64 + t];
    ksum[bh * 64 + t] = s;
  }
}

// ---------------- att = (q' @ KV) * z, written in the reference's reshape ---
__global__ __launch_bounds__(256) void att_k(
    const unsigned short* __restrict__ Qp, const unsigned short* __restrict__ KVT,
    const float* __restrict__ ksum, unsigned short* __restrict__ att) {
  __shared__ unsigned short Ql[128 * 64];
  __shared__ unsigned short Kl[64 * 64];
  __shared__ float ksl[64];
  __shared__ float zl[128];
  int bh = blockIdx.y;
  int b = bh >> 4, h = bh & 15;
  int r0 = blockIdx.x * 128;
  int t = threadIdx.x, lane = t & 63, wid = t >> 6;
  int l15 = lane & 15, lhi = lane >> 4;
  #pragma unroll
  for (int i = 0; i < 4; ++i) {
    int cid = i * 256 + t;
    int r = cid >> 3, c8 = cid & 7;
    gload16(Qp + ((size_t)(b * S_LEN + r0 + r)) * D_MODEL + h * DEPTH + c8 * 8,
            &Ql[cid * 8]);
  }
  #pragma unroll
  for (int i = 0; i < 2; ++i) {
    int cid = i * 256 + t;
    gload16(KVT + (size_t)bh * 4096 + cid * 8, &Kl[cid * 8]);
  }
  if (t < 64) ksl[t] = ksum[bh * 64 + t];
  asm volatile("s_waitcnt vmcnt(0)" ::: "memory");
  __syncthreads();
  {
    int r = t >> 1, half = t & 1;
    float s = 0.f;
    #pragma unroll
    for (int j = 0; j < 32; ++j)
      s += bf2f(Ql[r * 64 + half * 32 + j]) * ksl[half * 32 + j];
    s += __shfl_xor(s, 1);
    if (half == 0) zl[r] = 1.f / (s + EPS_K_F);
  }
  __syncthreads();
  f32x4 acc[2][4] = {};
  #pragma unroll
  for (int kk = 0; kk < 2; ++kk) {
    short8 af[2], bfr[4];
    #pragma unroll
    for (int m = 0; m < 2; ++m)
      af[m] = *(const short8*)&Ql[(wid * 32 + m * 16 + l15) * 64 + kk * 32 + lhi * 8];
    #pragma unroll
    for (int n = 0; n < 4; ++n)
      bfr[n] = *(const short8*)&Kl[(n * 16 + l15) * 64 + kk * 32 + lhi * 8];
    #pragma unroll
    for (int m = 0; m < 2; ++m)
      #pragma unroll
      for (int n = 0; n < 4; ++n)
        acc[m][n] = __builtin_amdgcn_mfma_f32_16x16x32_bf16(af[m], bfr[n], acc[m][n], 0, 0, 0);
  }
  #pragma unroll
  for (int m = 0; m < 2; ++m)
    #pragma unroll
    for (int j = 0; j < 4; ++j) {
      int rl = wid * 32 + m * 16 + lhi * 4 + j;
      int n = r0 + rl;
      float z = zl[rl];
      #pragma unroll
      for (int nf = 0; nf < 4; ++nf) {
        int ee = nf * 16 + l15;
        size_t orow = (size_t)b * S_LEN + h * 256 + (n >> 4);
        int ocol = (n & 15) * 64 + ee;
        att[orow * D_MODEL + ocol] = f2bf(acc[m][nf][j] * z);
      }
    }
}

extern "C" void kernel_launch(void* const* d_in, const int* in_sizes, int n_in,
                              void* d_out, int out_size, void* d_ws, size_t ws_size,
                              hipStream_t stream) {
  (void)in_sizes; (void)n_in; (void)out_size; (void)ws_size;
  const float* q     = (const float*)d_in[0];
  const float* k     = (const float*)d_in[1];
  const float* v     = (const float*)d_in[2];
  const float* mask  = (const float*)d_in[3];
  const float* wq    = (const float*)d_in[4];
  const float* wk    = (const float*)d_in[5];
  const float* wv    = (const float*)d_in[6];
  const float* gamma = (const float*)d_in[7];
  const float* beta  = (const float*)d_in[8];
  const float* dw    = (const float*)d_in[9];
  const float* db    = (const float*)d_in[10];
  float* out = (float*)d_out;

  char* ws = (char*)d_ws;
  // buffer plan (lifetimes hand-verified):
  //   ws+0   : Xq (cvt) -> dead after gemm_q -> Qp (ln_act) -> dead after
  //            att -> Cd (dense C).
  //   ws+32M : Xk (gemm_q sidecar) -> dead after gemm_k -> Kp (ln_act)
  //            -> dead after kv_mfma.
  //   ws+64M : Xv (gemm_k sidecar) -> dead after gemm_v -> Vp (ln_act)
  //            -> dead after kv_mfma.
  //   ws+96M : weights; ws+104M: part; ws+112M: kspart/KVT/ksum; psum/psq.
  //   d_out  : bf16 C scratch for q/k/v GEMMs + att output (first 32 MB),
  //            fully overwritten by ln_final at the end.
  unsigned short* Xq  = (unsigned short*)(ws);
  unsigned short* Xk  = (unsigned short*)(ws + 33554432);
  unsigned short* Xv  = (unsigned short*)(ws + 67108864);
  unsigned short* Qp  = Xq;
  unsigned short* Kp  = Xk;
  unsigned short* Vp  = Xv;
  unsigned short* Cd  = Xq;                 // dense C after att consumed Qp
  unsigned short* WqT = (unsigned short*)(ws + 100663296);
  unsigned short* WkT = WqT + 1048576;
  unsigned short* WvT = WkT + 1048576;
  unsigned short* WdT = WvT + 1048576;
  float* part   = (float*)(ws + 109051904);
  float* kspart = (float*)(ws + 117440512);
  unsigned short* KVT = (unsigned short*)(ws + 117964800);
  float* ksum = (float*)(ws + 118489088);
  float* psum = (float*)(ws + 119537664);   // 1 MB
  float* psq  = (float*)(ws + 120586240);   // 1 MB
  unsigned short* Cqkv = (unsigned short*)d_out;   // bf16 C scratch / att out

  dim3 b256(256);
  dim3 b512(512);
  int n4 = ROWS * D_MODEL / 4;
  dim3 cvtg(n4 / 256);
  dim3 wtg(32, 32);
  dim3 gemmg(256);            // (M/256)*(N/256), XCD-swizzled in-kernel
  dim3 lng(ROWS);

  wtrans_k<<<wtg, b256, 0, stream>>>(wq, WqT);
  wtrans_k<<<wtg, b256, 0, stream>>>(wk, WkT);
  wtrans_k<<<wtg, b256, 0, stream>>>(wv, WvT);
  wtrans_k<<<wtg, b256, 0, stream>>>(dw, WdT);

  cvt_f32_bf16_k<<<cvtg, b256, 0, stream>>>(q, Xq, n4);

  // gemm_q: sidecar converts k -> Xk
  gemm_bt_k<true><<<gemmg, b512, 0, stream>>>(Xq, WqT, Cqkv, psum, psq, nullptr,
                                              k, Xk, ROWS, D_MODEL, D_MODEL);
  ln_act_k<<<lng, b256, 0, stream>>>(Cqkv, psum, psq, gamma, beta, nullptr, Qp, 0);

  // gemm_k: sidecar converts v -> Xv
  gemm_bt_k<true><<<gemmg, b512, 0, stream>>>(Xk, WkT, Cqkv, psum, psq, nullptr,
                                              v, Xv, ROWS, D_MODEL, D_MODEL);
  ln_act_k<<<lng, b256, 0, stream>>>(Cqkv, psum, psq, gamma, beta, mask, Kp, 1);

  gemm_bt_k<false><<<gemmg, b512, 0, stream>>>(Xv, WvT, Cqkv, psum, psq, nullptr,
                                               nullptr, nullptr, ROWS, D_MODEL, D_MODEL);
  ln_act_k<<<lng, b256, 0, stream>>>(Cqkv, psum, psq, gamma, beta, mask, Vp, 2);

  kv_mfma_k<<<dim3(8, 64), b256, 0, stream>>>(Kp, Vp, part, kspart);
  kv_reduce_k<<<dim3(64), b256, 0, stream>>>(part, kspart, KVT, ksum);
  att_k<<<dim3(32, 64), b256, 0, stream>>>(Qp, KVT, ksum, Cqkv);

  gemm_bt_k<false><<<gemmg, b512, 0, stream>>>(Cqkv, WdT, Cd, psum, psq, db,
                                               nullptr, nullptr, ROWS, D_MODEL, D_MODEL);
  ln_final_k<<<lng, b256, 0, stream>>>(Cd, psum, psq, gamma, beta, out);
}

// Round 13
// 347.292 us; speedup vs baseline: 1.0622x; 1.0173x over previous
//
#include <hip/hip_runtime.h>
#include <hip/hip_bf16.h>
#include <stdint.h>

#define D_MODEL 1024
#define S_LEN   4096
#define BATCH   4
#define HEADS   16
#define DEPTH   64
#define ROWS    (BATCH*S_LEN)   // 16384
#define EPS_K_F 1e-6f
#define EPS_LN_F 1e-6f

typedef __attribute__((ext_vector_type(8))) short short8;
typedef __attribute__((ext_vector_type(4))) float f32x4;

__device__ __forceinline__ unsigned short f2bf(float f) {
  union { float f; unsigned u; } x; x.f = f;
  unsigned r = x.u + 0x7FFF + ((x.u >> 16) & 1);
  return (unsigned short)(r >> 16);
}
__device__ __forceinline__ float bf2f(unsigned short b) {
  union { unsigned u; float f; } x; x.u = ((unsigned)b) << 16;
  return x.f;
}
__device__ __forceinline__ void gload16(const void* g, void* l) {
  __builtin_amdgcn_global_load_lds(
      (const __attribute__((address_space(1))) void*)g,
      (__attribute__((address_space(3))) void*)l, 16, 0, 0);
}

// ---------------- f32 -> bf16 convert (q only; k,v ride GEMM sidecars) ------
__global__ __launch_bounds__(256) void cvt_f32_bf16_k(
    const float* __restrict__ in, unsigned short* __restrict__ out, int n4) {
  int i = blockIdx.x * 256 + threadIdx.x;
  if (i < n4) {
    float4 v = ((const float4*)in)[i];
    ushort4 o;
    o.x = f2bf(v.x); o.y = f2bf(v.y); o.z = f2bf(v.z); o.w = f2bf(v.w);
    ((ushort4*)out)[i] = o;
  }
}

// ---------------- weight transpose + convert: W[K,N] f32 -> Wt[N,K] bf16 ----
__global__ __launch_bounds__(256) void wtrans_k(
    const float* __restrict__ W, unsigned short* __restrict__ Wt) {
  __shared__ float tile[32][33];
  int n0 = blockIdx.x * 32, k0 = blockIdx.y * 32;
  int tx = threadIdx.x & 31, ty = threadIdx.x >> 5;
  #pragma unroll
  for (int i = 0; i < 32; i += 8)
    tile[ty + i][tx] = W[(size_t)(k0 + ty + i) * D_MODEL + n0 + tx];
  __syncthreads();
  #pragma unroll
  for (int i = 0; i < 32; i += 8)
    Wt[(size_t)(n0 + ty + i) * D_MODEL + k0 + tx] = f2bf(tile[tx][ty + i]);
}

// ===== GEMM: 256x256 tile, 8 waves, BK=64, counted-vmcnt 4-phase pipeline ===
// LDS per tensor: [2 slots][2 kk-halves][256 rows x 32 k] bf16 (128 KB).
// Swizzle within a half (involution on both sides, R13 fix): LDS slot s of
// row r holds global chunk s ^ ((r>>1)&3). Bank map: 16-lane group covers
// all 8 4-bank groups exactly 2x (2-way aliasing = free; old (r&3) form was
// 4-way on even lanes -> 3.1M conflict cycles/dispatch).
// Main loop peeled (staging unconditional); counted waits: boundary
// vmcnt(8) [sidecar: vmcnt(11)] keeps next tile's loads in flight.

#define GEMM_EPILOGUE(HASBIAS)                                               \
  if (HASBIAS) {                                                             \
    float bv[4];                                                             \
    _Pragma("unroll")                                                        \
    for (int n = 0; n < 4; ++n)                                              \
      bv[n] = bias[(int)n0 + wcn * 64 + n * 16 + l15];                       \
    _Pragma("unroll")                                                        \
    for (int m = 0; m < 8; ++m)                                              \
      _Pragma("unroll")                                                      \
      for (int n = 0; n < 4; ++n)                                            \
        _Pragma("unroll")                                                    \
        for (int j = 0; j < 4; ++j)                                          \
          acc[m][n][j] += bv[n];                                             \
  }                                                                          \
  int seg = (int)(n0 >> 6) + wcn;                                            \
  _Pragma("unroll")                                                          \
  for (int m = 0; m < 8; ++m) {                                              \
    float s[4], s2[4];                                                       \
    _Pragma("unroll")                                                        \
    for (int j = 0; j < 4; ++j) {                                            \
      float a = 0.f, b = 0.f;                                                \
      _Pragma("unroll")                                                      \
      for (int n = 0; n < 4; ++n) { float x = acc[m][n][j]; a += x; b += x*x; } \
      s[j] = a; s2[j] = b;                                                   \
    }                                                                        \
    _Pragma("unroll")                                                        \
    for (int off = 1; off < 16; off <<= 1) {                                 \
      _Pragma("unroll")                                                      \
      for (int j = 0; j < 4; ++j) {                                          \
        s[j]  += __shfl_xor(s[j],  off);                                     \
        s2[j] += __shfl_xor(s2[j], off);                                     \
      }                                                                      \
    }                                                                        \
    if (l15 == 0) {                                                          \
      _Pragma("unroll")                                                      \
      for (int j = 0; j < 4; ++j) {                                          \
        int rg = (int)m0 + wr * 128 + m * 16 + lhi * 4 + j;                  \
        psum[rg * 16 + seg] = s[j];                                          \
        psq [rg * 16 + seg] = s2[j];                                         \
      }                                                                      \
    }                                                                        \
  }                                                                          \
  _Pragma("unroll")                                                          \
  for (int m = 0; m < 8; ++m)                                                \
    _Pragma("unroll")                                                        \
    for (int j = 0; j < 4; ++j) {                                            \
      size_t row = m0 + wr * 128 + m * 16 + lhi * 4 + j;                     \
      _Pragma("unroll")                                                      \
      for (int n = 0; n < 4; ++n) {                                          \
        int col = (int)n0 + wcn * 64 + n * 16 + l15;                         \
        Cb[row * N + col] = f2bf(acc[m][n][j]);                              \
      }                                                                      \
    }

#define STAGE_HALF(kof_, slot_, h_) do {                                     \
    _Pragma("unroll")                                                        \
    for (int j = 0; j < 2; ++j) {                                            \
      int idx = j * 512 + t; int r_ = idx >> 2; int cs_ = idx & 3;           \
      int c_ = cs_ ^ ((r_ >> 1) & 3);                                        \
      gload16(A + (m0 + r_) * (size_t)K + (kof_) + (h_) * 32 + c_ * 8,       \
              &Al[slot_][(h_) * 8192 + idx * 8]);                            \
    }                                                                        \
    _Pragma("unroll")                                                        \
    for (int j = 0; j < 2; ++j) {                                            \
      int idx = j * 512 + t; int r_ = idx >> 2; int cs_ = idx & 3;           \
      int c_ = cs_ ^ ((r_ >> 1) & 3);                                        \
      gload16(Bt + (n0 + r_) * (size_t)K + (kof_) + (h_) * 32 + c_ * 8,      \
              &Bl[slot_][(h_) * 8192 + idx * 8]);                            \
    }                                                                        \
  } while (0)

#define PH_READ_B(kk_)                                                       \
    _Pragma("unroll")                                                        \
    for (int n = 0; n < 4; ++n) {                                            \
      int rb_ = wcn * 64 + n * 16 + l15;                                     \
      bfr[n] = *(const short8*)&Bl[slot][(kk_) * 8192 + rb_ * 32 + cswz];    \
    }
#define PH_READ_A(kk_, mh_)                                                  \
    _Pragma("unroll")                                                        \
    for (int m = 0; m < 4; ++m) {                                            \
      int ra_ = wr * 128 + ((mh_) * 4 + m) * 16 + l15;                       \
      af[m] = *(const short8*)&Al[slot][(kk_) * 8192 + ra_ * 32 + cswz];     \
    }
#define PH_MFMA(mh_)                                                         \
    __builtin_amdgcn_s_setprio(1);                                           \
    _Pragma("unroll")                                                        \
    for (int m = 0; m < 4; ++m)                                              \
      _Pragma("unroll")                                                      \
      for (int n = 0; n < 4; ++n)                                            \
        acc[(mh_) * 4 + m][n] = __builtin_amdgcn_mfma_f32_16x16x32_bf16(     \
            af[m], bfr[n], acc[(mh_) * 4 + m][n], 0, 0, 0);                  \
    __builtin_amdgcn_s_setprio(0);
#define LGKM0                                                                \
    asm volatile("s_waitcnt lgkmcnt(0)" ::: "memory");                       \
    __builtin_amdgcn_sched_barrier(0);

#define SIDE_PACK_STORE(chunk_) do {                                         \
    uint4 pk_;                                                               \
    pk_.x = (unsigned)f2bf(sreg0.x) | ((unsigned)f2bf(sreg0.y) << 16);       \
    pk_.y = (unsigned)f2bf(sreg0.z) | ((unsigned)f2bf(sreg0.w) << 16);       \
    pk_.z = (unsigned)f2bf(sreg1.x) | ((unsigned)f2bf(sreg1.y) << 16);       \
    pk_.w = (unsigned)f2bf(sreg1.z) | ((unsigned)f2bf(sreg1.w) << 16);       \
    *(uint4*)(side_dst + sbase + (size_t)(chunk_) * 4096) = pk_;             \
  } while (0)
#define SIDE_LOAD(chunk_) do {                                               \
    const float* sp_ = side_src + sbase + (size_t)(chunk_) * 4096;           \
    sreg0 = *(const float4*)sp_; sreg1 = *(const float4*)(sp_ + 4);          \
  } while (0)

#define TAIL_TILE(slot_) do {                                                \
    const int slot = (slot_);                                                \
    short8 af[4], bfr[4];                                                    \
    PH_READ_B(0) PH_READ_A(0, 0) LGKM0 PH_MFMA(0)                            \
    PH_READ_A(0, 1) LGKM0 PH_MFMA(1)                                         \
    PH_READ_B(1) PH_READ_A(1, 0) LGKM0 PH_MFMA(0)                            \
    PH_READ_A(1, 1) LGKM0 PH_MFMA(1)                                         \
  } while (0)

template <bool SIDECAR>
__global__ __launch_bounds__(512) void gemm_bt_k(
    const unsigned short* __restrict__ A,
    const unsigned short* __restrict__ Bt,
    unsigned short* __restrict__ Cb,
    float* __restrict__ psum, float* __restrict__ psq,
    const float* __restrict__ bias,
    const float* __restrict__ side_src,      // f32 tensor to convert
    unsigned short* __restrict__ side_dst,   // bf16 destination
    int M, int N, int K) {
  __shared__ unsigned short Al[2][16384];
  __shared__ unsigned short Bl[2][16384];
  int t = threadIdx.x;
  int lane = t & 63, wid = t >> 6;
  int wr = wid >> 2, wcn = wid & 3;
  int l15 = lane & 15, lhi = lane >> 4;
  const int cswz = (lhi ^ ((l15 >> 1) & 3)) << 3;  // conflict-free (R13)
  int p = blockIdx.x;
  int cb = (p >> 3) & 3;
  int rb = (p & 7) | ((p >> 5) << 3);
  size_t m0 = (size_t)rb * 256, n0 = (size_t)cb * 256;
  f32x4 acc[8][4] = {};

  const int KT = K >> 6;                  // 16 K-tiles of 64 (K==1024)

  // sidecar: block p converts elems [p*65536,(p+1)*65536), 16 chunks of 4096
  float4 sreg0 = {}, sreg1 = {};
  size_t sbase = (size_t)p * 65536 + (size_t)t * 8;

  // prologue: chunk-0 load FIRST, then stage tiles 0,1; vmcnt(8) drains
  // chunk-0 loads + tile-0 staging, keeps tile-1 staging (8) in flight.
  if (SIDECAR) SIDE_LOAD(0);
  STAGE_HALF(0, 0, 0);  STAGE_HALF(0, 0, 1);
  STAGE_HALF(64, 1, 0); STAGE_HALF(64, 1, 1);
  asm volatile("s_waitcnt vmcnt(8)" ::: "memory");
  __builtin_amdgcn_s_barrier();
  __builtin_amdgcn_sched_barrier(0);

  for (int kt = 0; kt < KT - 2; ++kt) {
    const int slot = kt & 1;
    short8 af[4], bfr[4];
    // phase 1: kk0, mh0
    PH_READ_B(0)
    PH_READ_A(0, 0)
    LGKM0
    PH_MFMA(0)
    // phase 2: kk0, mh1 (+ stage half0 of tile kt+2 into this slot)
    PH_READ_A(0, 1)
    LGKM0
    __builtin_amdgcn_s_barrier();          // all waves done with kk0 reads
    __builtin_amdgcn_sched_barrier(0);
    STAGE_HALF((kt + 2) << 6, slot, 0);
    __builtin_amdgcn_sched_barrier(0);
    PH_MFMA(1)
    // phase 3: kk1, mh0
    PH_READ_B(1)
    PH_READ_A(1, 0)
    LGKM0
    PH_MFMA(0)
    // phase 4: kk1, mh1 (+ stage half1 of tile kt+2)
    PH_READ_A(1, 1)
    LGKM0
    __builtin_amdgcn_s_barrier();          // all waves done with kk1 reads
    __builtin_amdgcn_sched_barrier(0);
    STAGE_HALF((kt + 2) << 6, slot, 1);
    __builtin_amdgcn_sched_barrier(0);
    PH_MFMA(1)
    // boundary
    if (SIDECAR) {
      // pack chunk kt (compiler's wait for sreg == vmcnt(8): also drains
      // stage(kt+1) by in-order retirement), store it, load chunk kt+1.
      SIDE_PACK_STORE(kt);
      SIDE_LOAD(kt + 1);
      __builtin_amdgcn_sched_barrier(0);
      asm volatile("s_waitcnt vmcnt(11)" ::: "memory");
    } else {
      asm volatile("s_waitcnt vmcnt(8)" ::: "memory");
    }
    __builtin_amdgcn_s_barrier();
    __builtin_amdgcn_sched_barrier(0);
  }

  // tail tile KT-2 (slot 0): no staging
  TAIL_TILE((KT - 2) & 1);
  if (SIDECAR) {
    SIDE_PACK_STORE(KT - 2);
    SIDE_LOAD(KT - 1);
    __builtin_amdgcn_sched_barrier(0);
    asm volatile("s_waitcnt vmcnt(3)" ::: "memory");  // drain stage(KT-1)
  } else {
    asm volatile("s_waitcnt vmcnt(0)" ::: "memory");
  }
  __builtin_amdgcn_s_barrier();
  __builtin_amdgcn_sched_barrier(0);

  // tail tile KT-1 (slot 1): no staging, no boundary
  TAIL_TILE((KT - 1) & 1);
  if (SIDECAR) SIDE_PACK_STORE(KT - 1);

  GEMM_EPILOGUE(bias != nullptr)
}

// ---------------- LN + activation from bf16 C + partials -> bf16 ------------
// mode 0: relu(ln)+eps ; mode 1: (relu(ln)+eps)*mask ; mode 2: ln*mask
__global__ __launch_bounds__(256) void ln_act_k(
    const unsigned short* __restrict__ Cb,
    const float* __restrict__ psum, const float* __restrict__ psq,
    const float* __restrict__ gamma, const float* __restrict__ beta,
    const float* __restrict__ mask,
    unsigned short* __restrict__ out, int mode) {
  int row = blockIdx.x;
  int t = threadIdx.x;
  float s = 0.f, s2 = 0.f;
  #pragma unroll
  for (int i = 0; i < 16; ++i) { s += psum[row * 16 + i]; s2 += psq[row * 16 + i]; }
  float mean = s * (1.f / D_MODEL);
  float var = s2 * (1.f / D_MODEL) - mean * mean;
  float rstd = rsqrtf(var + EPS_LN_F);
  float mk = (mode > 0) ? mask[row] : 1.f;
  ushort4 cv = ((const ushort4*)(Cb + (size_t)row * D_MODEL))[t];
  float4 gv = ((const float4*)gamma)[t];
  float4 bv = ((const float4*)beta)[t];
  float av[4] = {bf2f(cv.x), bf2f(cv.y), bf2f(cv.z), bf2f(cv.w)};
  float g4[4] = {gv.x, gv.y, gv.z, gv.w};
  float b4[4] = {bv.x, bv.y, bv.z, bv.w};
  unsigned short ov[4];
  #pragma unroll
  for (int j = 0; j < 4; ++j) {
    float ln = (av[j] - mean) * rstd * g4[j] + b4[j];
    if (mode == 0)      ln = fmaxf(ln, 0.f) + EPS_K_F;
    else if (mode == 1) ln = (fmaxf(ln, 0.f) + EPS_K_F) * mk;
    else                ln = ln * mk;
    ov[j] = f2bf(ln);
  }
  ushort4 o; o.x = ov[0]; o.y = ov[1]; o.z = ov[2]; o.w = ov[3];
  ((ushort4*)(out + (size_t)row * D_MODEL))[t] = o;
}

// ---------------- final LayerNorm from bf16 C + partials -> f32 out ---------
__global__ __launch_bounds__(256) void ln_final_k(
    const unsigned short* __restrict__ Cb,
    const float* __restrict__ psum, const float* __restrict__ psq,
    const float* __restrict__ gamma, const float* __restrict__ beta,
    float* __restrict__ out) {
  int row = blockIdx.x;
  int t = threadIdx.x;
  float s = 0.f, s2 = 0.f;
  #pragma unroll
  for (int i = 0; i < 16; ++i) { s += psum[row * 16 + i]; s2 += psq[row * 16 + i]; }
  float mean = s * (1.f / D_MODEL);
  float var = s2 * (1.f / D_MODEL) - mean * mean;
  float rstd = rsqrtf(var + EPS_LN_F);
  ushort4 cv = ((const ushort4*)(Cb + (size_t)row * D_MODEL))[t];
  float4 gv = ((const float4*)gamma)[t];
  float4 bv = ((const float4*)beta)[t];
  float4 w;
  w.x = (bf2f(cv.x) - mean) * rstd * gv.x + bv.x;
  w.y = (bf2f(cv.y) - mean) * rstd * gv.y + bv.y;
  w.z = (bf2f(cv.z) - mean) * rstd * gv.z + bv.z;
  w.w = (bf2f(cv.w) - mean) * rstd * gv.w + bv.w;
  ((float4*)(out + (size_t)row * D_MODEL))[t] = w;
}

// ---------------- KV via MFMA with swizzled-LDS transpose -------------------
__global__ __launch_bounds__(256) void kv_mfma_k(
    const unsigned short* __restrict__ Kp, const unsigned short* __restrict__ Vp,
    float* __restrict__ part, float* __restrict__ kspart) {
  __shared__ unsigned short Kl[4096];
  __shared__ unsigned short Vl[4096];
  int bh = blockIdx.y, chunk = blockIdx.x;   // chunk 0..7, 512 n each
  int b_ = bh >> 4, h = bh & 15;
  int t = threadIdx.x, lane = t & 63, w = t >> 6;
  int l15 = lane & 15, g = lane >> 4;        // g in 0..3

  int sn = t >> 2, sd16 = t & 3;
  int sc = sd16 ^ ((sn >> 3) & 3);
  size_t goff = (size_t)sn * D_MODEL + h * DEPTH + sd16 * 16;
  int ldst = sn * 64 + sc * 16;

  short8 ones;
  #pragma unroll
  for (int i = 0; i < 8; ++i) ones[i] = (short)0x3F80;

  f32x4 acc[4] = {};
  f32x4 ks = {};

  int baseA = ((w ^ g) << 4) + l15;
  int baseB0 = ((0 ^ g) << 4) + l15;
  int baseB1 = ((1 ^ g) << 4) + l15;
  int baseB2 = ((2 ^ g) << 4) + l15;
  int baseB3 = ((3 ^ g) << 4) + l15;

  size_t rowbase = ((size_t)b_ * S_LEN + (size_t)chunk * 512) * D_MODEL;
  for (int tile = 0; tile < 8; ++tile) {
    const unsigned short* kg = Kp + rowbase + (size_t)tile * 64 * D_MODEL + goff;
    const unsigned short* vg = Vp + rowbase + (size_t)tile * 64 * D_MODEL + goff;
    uint4 ra = *(const uint4*)kg;
    uint4 rb = *(const uint4*)(kg + 8);
    uint4 rc = *(const uint4*)vg;
    uint4 rd = *(const uint4*)(vg + 8);
    __syncthreads();
    *(uint4*)&Kl[ldst]     = ra;
    *(uint4*)&Kl[ldst + 8] = rb;
    *(uint4*)&Vl[ldst]     = rc;
    *(uint4*)&Vl[ldst + 8] = rd;
    __syncthreads();
    #pragma unroll
    for (int kk = 0; kk < 2; ++kk) {
      int nb = (kk * 32 + g * 8) * 64;
      short8 af, bf0, bf1, bf2, bf3;
      #pragma unroll
      for (int i = 0; i < 8; ++i) {
        int rowoff = nb + i * 64;
        af[i]  = (short)Kl[rowoff + baseA];
        bf0[i] = (short)Vl[rowoff + baseB0];
        bf1[i] = (short)Vl[rowoff + baseB1];
        bf2[i] = (short)Vl[rowoff + baseB2];
        bf3[i] = (short)Vl[rowoff + baseB3];
      }
      acc[0] = __builtin_amdgcn_mfma_f32_16x16x32_bf16(af, bf0, acc[0], 0, 0, 0);
      acc[1] = __builtin_amdgcn_mfma_f32_16x16x32_bf16(af, bf1, acc[1], 0, 0, 0);
      acc[2] = __builtin_amdgcn_mfma_f32_16x16x32_bf16(af, bf2, acc[2], 0, 0, 0);
      acc[3] = __builtin_amdgcn_mfma_f32_16x16x32_bf16(af, bf3, acc[3], 0, 0, 0);
      ks     = __builtin_amdgcn_mfma_f32_16x16x32_bf16(af, ones, ks, 0, 0, 0);
    }
  }
  float* pp = part + ((size_t)bh * 8 + chunk) * 4096;
  #pragma unroll
  for (int nf = 0; nf < 4; ++nf)
    #pragma unroll
    for (int r = 0; r < 4; ++r)
      pp[(16 * w + 4 * g + r) * 64 + 16 * nf + l15] = acc[nf][r];
  if (l15 == 0) {
    #pragma unroll
    for (int r = 0; r < 4; ++r)
      kspart[((size_t)bh * 8 + chunk) * 64 + 16 * w + 4 * g + r] = ks[r];
  }
}

// ---------------- KV reduce -> KV^T bf16 ([e][d]) + ksum f32 ----------------
__global__ __launch_bounds__(256) void kv_reduce_k(
    const float* __restrict__ part, const float* __restrict__ kspart,
    unsigned short* __restrict__ KVT, float* __restrict__ ksum) {
  int bh = blockIdx.x, t = threadIdx.x;
  for (int idx = t; idx < 4096; idx += 256) {
    int d = idx >> 6, e = idx & 63;
    float s = 0.f;
    #pragma unroll
    for (int c = 0; c < 8; ++c)
      s += part[((size_t)bh * 8 + c) * 4096 + d * 64 + e];
    KVT[(size_t)bh * 4096 + e * 64 + d] = f2bf(s);
  }
  if (t < 64) {
    float s = 0.f;
    #pragma unroll
    for (int c = 0; c < 8; ++c) s += kspart[((size_t)bh * 8 + c) * 64 + t];
    ksum[bh * 64 + t] = s;
  }
}

// ---------------- att = (q' @ KV) * z, written in the reference's reshape ---
__global__ __launch_bounds__(256) void att_k(
    const unsigned short* __restrict__ Qp, const unsigned short* __restrict__ KVT,
    const float* __restrict__ ksum, unsigned short* __restrict__ att) {
  __shared__ unsigned short Ql[128 * 64];
  __shared__ unsigned short Kl[64 * 64];
  __shared__ float ksl[64];
  __shared__ float zl[128];
  int bh = blockIdx.y;
  int b = bh >> 4, h = bh & 15;
  int r0 = blockIdx.x * 128;
  int t = threadIdx.x, lane = t & 63, wid = t >> 6;
  int l15 = lane & 15, lhi = lane >> 4;
  #pragma unroll
  for (int i = 0; i < 4; ++i) {
    int cid = i * 256 + t;
    int r = cid >> 3, c8 = cid & 7;
    gload16(Qp + ((size_t)(b * S_LEN + r0 + r)) * D_MODEL + h * DEPTH + c8 * 8,
            &Ql[cid * 8]);
  }
  #pragma unroll
  for (int i = 0; i < 2; ++i) {
    int cid = i * 256 + t;
    gload16(KVT + (size_t)bh * 4096 + cid * 8, &Kl[cid * 8]);
  }
  if (t < 64) ksl[t] = ksum[bh * 64 + t];
  asm volatile("s_waitcnt vmcnt(0)" ::: "memory");
  __syncthreads();
  {
    int r = t >> 1, half = t & 1;
    float s = 0.f;
    #pragma unroll
    for (int j = 0; j < 32; ++j)
      s += bf2f(Ql[r * 64 + half * 32 + j]) * ksl[half * 32 + j];
    s += __shfl_xor(s, 1);
    if (half == 0) zl[r] = 1.f / (s + EPS_K_F);
  }
  __syncthreads();
  f32x4 acc[2][4] = {};
  #pragma unroll
  for (int kk = 0; kk < 2; ++kk) {
    short8 af[2], bfr[4];
    #pragma unroll
    for (int m = 0; m < 2; ++m)
      af[m] = *(const short8*)&Ql[(wid * 32 + m * 16 + l15) * 64 + kk * 32 + lhi * 8];
    #pragma unroll
    for (int n = 0; n < 4; ++n)
      bfr[n] = *(const short8*)&Kl[(n * 16 + l15) * 64 + kk * 32 + lhi * 8];
    #pragma unroll
    for (int m = 0; m < 2; ++m)
      #pragma unroll
      for (int n = 0; n < 4; ++n)
        acc[m][n] = __builtin_amdgcn_mfma_f32_16x16x32_bf16(af[m], bfr[n], acc[m][n], 0, 0, 0);
  }
  #pragma unroll
  for (int m = 0; m < 2; ++m)
    #pragma unroll
    for (int j = 0; j < 4; ++j) {
      int rl = wid * 32 + m * 16 + lhi * 4 + j;
      int n = r0 + rl;
      float z = zl[rl];
      #pragma unroll
      for (int nf = 0; nf < 4; ++nf) {
        int ee = nf * 16 + l15;
        size_t orow = (size_t)b * S_LEN + h * 256 + (n >> 4);
        int ocol = (n & 15) * 64 + ee;
        att[orow * D_MODEL + ocol] = f2bf(acc[m][nf][j] * z);
      }
    }
}

extern "C" void kernel_launch(void* const* d_in, const int* in_sizes, int n_in,
                              void* d_out, int out_size, void* d_ws, size_t ws_size,
                              hipStream_t stream) {
  (void)in_sizes; (void)n_in; (void)out_size; (void)ws_size;
  const float* q     = (const float*)d_in[0];
  const float* k     = (const float*)d_in[1];
  const float* v     = (const float*)d_in[2];
  const float* mask  = (const float*)d_in[3];
  const float* wq    = (const float*)d_in[4];
  const float* wk    = (const float*)d_in[5];
  const float* wv    = (const float*)d_in[6];
  const float* gamma = (const float*)d_in[7];
  const float* beta  = (const float*)d_in[8];
  const float* dw    = (const float*)d_in[9];
  const float* db    = (const float*)d_in[10];
  float* out = (float*)d_out;

  char* ws = (char*)d_ws;
  // buffer plan (lifetimes hand-verified):
  //   ws+0   : Xq (cvt) -> dead after gemm_q -> Qp (ln_act) -> dead after
  //            att -> Cd (dense C).
  //   ws+32M : Xk (gemm_q sidecar) -> dead after gemm_k -> Kp (ln_act)
  //            -> dead after kv_mfma.
  //   ws+64M : Xv (gemm_k sidecar) -> dead after gemm_v -> Vp (ln_act)
  //            -> dead after kv_mfma.
  //   ws+96M : weights; ws+104M: part; ws+112M: kspart/KVT/ksum; psum/psq.
  //   d_out  : bf16 C scratch for q/k/v GEMMs + att output (first 32 MB),
  //            fully overwritten by ln_final at the end.
  unsigned short* Xq  = (unsigned short*)(ws);
  unsigned short* Xk  = (unsigned short*)(ws + 33554432);
  unsigned short* Xv  = (unsigned short*)(ws + 67108864);
  unsigned short* Qp  = Xq;
  unsigned short* Kp  = Xk;
  unsigned short* Vp  = Xv;
  unsigned short* Cd  = Xq;                 // dense C after att consumed Qp
  unsigned short* WqT = (unsigned short*)(ws + 100663296);
  unsigned short* WkT = WqT + 1048576;
  unsigned short* WvT = WkT + 1048576;
  unsigned short* WdT = WvT + 1048576;
  float* part   = (float*)(ws + 109051904);
  float* kspart = (float*)(ws + 117440512);
  unsigned short* KVT = (unsigned short*)(ws + 117964800);
  float* ksum = (float*)(ws + 118489088);
  float* psum = (float*)(ws + 119537664);   // 1 MB
  float* psq  = (float*)(ws + 120586240);   // 1 MB
  unsigned short* Cqkv = (unsigned short*)d_out;   // bf16 C scratch / att out

  dim3 b256(256);
  dim3 b512(512);
  int n4 = ROWS * D_MODEL / 4;
  dim3 cvtg(n4 / 256);
  dim3 wtg(32, 32);
  dim3 gemmg(256);            // (M/256)*(N/256), XCD-swizzled in-kernel
  dim3 lng(ROWS);

  wtrans_k<<<wtg, b256, 0, stream>>>(wq, WqT);
  wtrans_k<<<wtg, b256, 0, stream>>>(wk, WkT);
  wtrans_k<<<wtg, b256, 0, stream>>>(wv, WvT);
  wtrans_k<<<wtg, b256, 0, stream>>>(dw, WdT);

  cvt_f32_bf16_k<<<cvtg, b256, 0, stream>>>(q, Xq, n4);

  // gemm_q: sidecar converts k -> Xk
  gemm_bt_k<true><<<gemmg, b512, 0, stream>>>(Xq, WqT, Cqkv, psum, psq, nullptr,
                                              k, Xk, ROWS, D_MODEL, D_MODEL);
  ln_act_k<<<lng, b256, 0, stream>>>(Cqkv, psum, psq, gamma, beta, nullptr, Qp, 0);

  // gemm_k: sidecar converts v -> Xv
  gemm_bt_k<true><<<gemmg, b512, 0, stream>>>(Xk, WkT, Cqkv, psum, psq, nullptr,
                                              v, Xv, ROWS, D_MODEL, D_MODEL);
  ln_act_k<<<lng, b256, 0, stream>>>(Cqkv, psum, psq, gamma, beta, mask, Kp, 1);

  gemm_bt_k<false><<<gemmg, b512, 0, stream>>>(Xv, WvT, Cqkv, psum, psq, nullptr,
                                               nullptr, nullptr, ROWS, D_MODEL, D_MODEL);
  ln_act_k<<<lng, b256, 0, stream>>>(Cqkv, psum, psq, gamma, beta, mask, Vp, 2);

  kv_mfma_k<<<dim3(8, 64), b256, 0, stream>>>(Kp, Vp, part, kspart);
  kv_reduce_k<<<dim3(64), b256, 0, stream>>>(part, kspart, KVT, ksum);
  att_k<<<dim3(32, 64), b256, 0, stream>>>(Qp, KVT, ksum, Cqkv);

  gemm_bt_k<false><<<gemmg, b512, 0, stream>>>(Cqkv, WdT, Cd, psum, psq, db,
                                               nullptr, nullptr, ROWS, D_MODEL, D_MODEL);
  ln_final_k<<<lng, b256, 0, stream>>>(Cd, psum, psq, gamma, beta, out);
}